// Round 11
// baseline (269.313 us; speedup 1.0000x reference)
//
#include <hip/hip_runtime.h>
#include <hip/hip_bf16.h>
#include <math.h>

#define B_ 512
#define N_ 32
#define D_ 300
#define R_ 6
#define E_ 256
#define NG_ 50000
#define NS_ 25000

#define KTOT 2100      // 6*300 (Wrel) + 300 (W0)
#define YLD  2112      // Y bf16 leading dim (33*64)
#define XLD  320       // X0H bf16 leading dim (5*64)
#define PLD  304       // k1b partial leading dim (fp32)
#define NCBG 782       // ceil(50000/64)
#define NCBS 391       // ceil(25000/64)
#define CPADG (NCBG*64)   // 50048
#define CPADS (NCBS*64)   // 25024
#define NTILE (NCBG+NCBS) // 1173

typedef __attribute__((ext_vector_type(8))) short short8;
typedef __attribute__((ext_vector_type(4))) float f32x4;

__device__ __forceinline__ unsigned short f2bf(float f) {
  __hip_bfloat16 h = __float2bfloat16(f);
  return *reinterpret_cast<unsigned short*>(&h);
}

__device__ __forceinline__ void gload_lds16(const unsigned short* g, unsigned short* l) {
  __builtin_amdgcn_global_load_lds(
      (const __attribute__((address_space(1))) void*)g,
      (__attribute__((address_space(3))) void*)l,
      16, 0, 0);
}

// ---------------- K1a: collapse graph to Y[b, 2112] bf16 (zero k-pad) ----------------
__global__ __launch_bounds__(256) void k1a_coef_y(
    const float* __restrict__ x, const int* __restrict__ ei,
    const int* __restrict__ et, unsigned short* __restrict__ Y)
{
  int b = blockIdx.x;
  int tid = threadIdx.x;
  __shared__ int srcs[E_], dsts[E_], ets[E_];
  __shared__ int degc[R_*N_];
  __shared__ float coef[R_*N_];

  srcs[tid] = ei[b*2*E_ + tid];
  dsts[tid] = ei[b*2*E_ + E_ + tid];
  ets[tid]  = et[b*E_ + tid];
  if (tid < R_*N_) { degc[tid] = 0; coef[tid] = 0.0f; }
  __syncthreads();

  atomicAdd(&degc[ets[tid]*N_ + dsts[tid]], 1);
  __syncthreads();

  if (dsts[tid] == 0) {
    int r = ets[tid];
    float ds = 1.0f + (float)degc[r*N_ + srcs[tid]];
    float dd = 1.0f + (float)degc[r*N_ + 0];
    atomicAdd(&coef[r*N_ + srcs[tid]], rsqrtf(ds*dd));
  }
  if (tid < R_) {
    atomicAdd(&coef[tid*N_ + 0], 1.0f/(1.0f + (float)degc[tid*N_]));
  }
  __syncthreads();

  const float* xb = x + (size_t)b*N_*D_;
  unsigned short* Yb = Y + (size_t)b*YLD;
  for (int k = tid; k < D_; k += 256) {
    #pragma unroll
    for (int r = 0; r < R_; ++r) {
      float acc = 0.0f;
      for (int n = 0; n < N_; ++n) {
        float c = coef[r*N_ + n];          // uniform across threads
        if (c != 0.0f) acc += c * xb[n*D_ + k];
      }
      Yb[r*D_ + k] = f2bf(acc);
    }
    Yb[6*D_ + k] = f2bf(xb[k]);            // x[b,0,:] for the W0 term
  }
  if (tid < YLD - KTOT) Yb[KTOT + tid] = 0;
}

// ---------------- k1b gemm (round-5 proven): BM=256, BN=64, BK=64 ----------------
__global__ __launch_bounds__(256, 3) void gemm_k1b(
    const unsigned short* __restrict__ A, int lda,
    const float* __restrict__ B0, const float* __restrict__ B1,
    float* __restrict__ P1, int nz)
{
  __shared__ unsigned short As[256*64];
  __shared__ unsigned short Bs[64*80];

  const int tid  = threadIdx.x;
  const int lane = tid & 63, wid = tid >> 6;
  const int lr = lane & 15, lg = lane >> 4;

  int id = blockIdx.x;          // 2 mb * 5 cb * nz
  int mb = id & 1; id >>= 1;
  int cb = id % 5, z = id / 5;
  const int m0 = mb*256, c0 = cb*64;
  const int ksplit = 6*D_;

  const int r8 = lane >> 3, sl = lane & 7;
  const int c_l = tid & 63, ob = tid >> 6;
  const int gcol = c0 + c_l;
  const bool cok = (gcol < D_);

  f32x4 acc[4][4];
  #pragma unroll
  for (int a = 0; a < 4; ++a)
    #pragma unroll
    for (int b = 0; b < 4; ++b) acc[a][b] = (f32x4){0.f,0.f,0.f,0.f};

  for (int t = z; t < 33; t += nz) {
    const int kt = t * 64;
    __syncthreads();

    #pragma unroll
    for (int i = 0; i < 8; ++i) {
      int row_l = wid*64 + i*8 + r8;
      int sslot = sl ^ (row_l & 7);
      gload_lds16(A + (size_t)(m0 + row_l)*lda + kt + sslot*8, &As[(wid*64 + i*8)*64]);
    }

    #pragma unroll
    for (int it = 0; it < 2; ++it) {
      int o  = ob + it*4;
      int kb = kt + o*8;
      unsigned short u[8];
      #pragma unroll
      for (int j = 0; j < 8; ++j) {
        int k = kb + j;
        float v = 0.f;
        if (cok && k < KTOT)
          v = (k < ksplit) ? B0[(size_t)k*D_ + gcol]
                           : B1[(size_t)(k - ksplit)*D_ + gcol];
        u[j] = f2bf(v);
      }
      *reinterpret_cast<short8*>(&Bs[c_l*80 + ((o ^ (c_l & 7)) << 3)]) =
          *reinterpret_cast<const short8*>(u);
    }

    __syncthreads();

    #pragma unroll
    for (int kk = 0; kk < 2; ++kk) {
      const int q = kk*4 + lg;
      short8 bfr[4];
      #pragma unroll
      for (int b = 0; b < 4; ++b) {
        int col = b*16 + lr;
        bfr[b] = *reinterpret_cast<const short8*>(&Bs[col*80 + ((q ^ (col & 7)) << 3)]);
      }
      #pragma unroll
      for (int a = 0; a < 4; ++a) {
        int row = wid*64 + a*16 + lr;
        short8 af = *reinterpret_cast<const short8*>(&As[row*64 + ((q ^ (row & 7)) << 3)]);
        #pragma unroll
        for (int b = 0; b < 4; ++b)
          acc[a][b] = __builtin_amdgcn_mfma_f32_16x16x32_bf16(af, bfr[b], acc[a][b], 0, 0, 0);
      }
    }
  }

  float* o = P1 + (size_t)z * (size_t)B_ * PLD;
  #pragma unroll
  for (int a = 0; a < 4; ++a) {
    int row = m0 + wid*64 + a*16 + lg*4;
    #pragma unroll
    for (int b = 0; b < 4; ++b) {
      int col = c0 + b*16 + lr;
      if (col < D_) {
        #pragma unroll
        for (int i = 0; i < 4; ++i)
          o[(size_t)(row + i)*PLD + col] = acc[a][b][i];
      }
    }
  }
}

// ---------------- K1c: reduce z-partials, leaky, emit bf16 X0H [512][320] ----------------
__global__ __launch_bounds__(256) void k1c_reduce(
    const float* __restrict__ part, int nz, unsigned short* __restrict__ X0Hbf)
{
  int idx = blockIdx.x*256 + threadIdx.x;
  if (idx >= B_*XLD) return;
  int m = idx / XLD, c = idx % XLD;
  float v = 0.f;
  if (c < D_) {
    for (int zz = 0; zz < nz; ++zz) v += part[(size_t)zz*B_*PLD + (size_t)m*PLD + c];
    v = (v >= 0.f) ? v : 0.1f*v;
  }
  X0Hbf[idx] = f2bf(v);
}

// ---------------- wtrans2: W[300][C] fp32 -> Wtt octet-major bf16 ----------------
__global__ __launch_bounds__(256) void wtrans2(
    const float* __restrict__ W, int C, int Cpad, unsigned short* __restrict__ Wtt)
{
  __shared__ float lds[64][65];
  const int tid = threadIdx.x;
  const int c0 = blockIdx.x * 64;
  const int k0 = blockIdx.y * 64;
  const int col = tid & 63;
  const int w = tid >> 6;

  #pragma unroll
  for (int p = 0; p < 16; ++p) {
    int kl = w*16 + p;
    int k = k0 + kl;
    float v = 0.f;
    if (k < D_ && c0 + col < C) v = W[(size_t)k*C + c0 + col];
    lds[kl][col] = v;
  }
  __syncthreads();

  #pragma unroll
  for (int q2 = 0; q2 < 2; ++q2) {
    int octl = w*2 + q2;
    unsigned short u[8];
    #pragma unroll
    for (int j = 0; j < 8; ++j) u[j] = f2bf(lds[octl*8 + j][col]);
    size_t goct = (size_t)(k0 >> 3) + octl;
    *reinterpret_cast<short8*>(&Wtt[(goct*Cpad + c0 + col) * 8]) =
        *reinterpret_cast<const short8*>(u);
  }
}

// ---------------- gemm10: heads. BM=512, W once, 5-deep DMA, drain-free waits ----
// 512 thr = 8 waves; wave owns 64 rows x K=320 in regs (af[4][10]).
// 6-buf LDS for B; DMA issued 5 stages ahead; waits: tile0 vmcnt(4), mid vmcnt(40)
// (=4 DMA + 36 epilogue vmem after the needed DMA), last 40..36 descending.
// Epilogue: acc -> per-wave LDS chunk -> 16 contiguous dwordx4 stores (256B/row).
__global__ __launch_bounds__(512, 1) void gemm10(
    const unsigned short* __restrict__ X0H,
    const unsigned short* __restrict__ Wttg, const unsigned short* __restrict__ Wtts,
    const float* __restrict__ bg, const float* __restrict__ bs,
    float* __restrict__ out, float2* __restrict__ Pg, float2* __restrict__ Ps)
{
  __shared__ unsigned short BsF[6*4096];   // 6 bufs x 8KB = 48 KB
  __shared__ float eplds[8][1088];         // 8 waves x (16 rows x 68 pad) = 34 KB

  const int bid = blockIdx.x;
  const int tid = threadIdx.x;
  const int lane = tid & 63, w = tid >> 6;
  const int lr = lane & 15, lg = lane >> 4;

  const int nt  = 1 + (NTILE - 1 - bid) / 256;   // 4 or 5 tiles

  auto dma = [&](int su2) {
    int tl2 = su2 / 5, j2 = su2 % 5;
    int tt2 = bid + tl2*256;
    const unsigned short* wt; size_t cp; int cb2;
    if (tt2 < NCBG) { wt = Wttg; cp = CPADG; cb2 = tt2; }
    else            { wt = Wtts; cp = CPADS; cb2 = tt2 - NCBG; }
    const unsigned short* g = wt + ((size_t)(j2*8 + w)*cp + (size_t)cb2*64 + lane)*8;
    gload_lds16(g, &BsF[(su2 % 6)*4096 + w*512]);
  };

  // ---- A into registers FIRST (so tile0 waits see clean DMA-only tail) ----
  short8 af[4][10];
  #pragma unroll
  for (int a = 0; a < 4; ++a) {
    const unsigned short* Ar = X0H + (size_t)(w*64 + a*16 + lr)*XLD + lg*8;
    #pragma unroll
    for (int ks = 0; ks < 10; ++ks)
      af[a][ks] = *reinterpret_cast<const short8*>(Ar + ks*32);
  }
  __builtin_amdgcn_sched_barrier(0);
  // prologue: 5 DMAs in flight
  dma(0); dma(1); dma(2); dma(3); dma(4);

  f32x4 acc[4][4];

#define MFMA10(j) do {                                                         \
    const unsigned short* bb = &BsF[((tl*5 + (j)) % 6)*4096];                  \
    _Pragma("unroll")                                                          \
    for (int kk = 0; kk < 2; ++kk) {                                           \
      short8 bfr[4];                                                           \
      _Pragma("unroll")                                                        \
      for (int b = 0; b < 4; ++b)                                              \
        bfr[b] = *reinterpret_cast<const short8*>(                             \
            &bb[(kk*4 + lg)*512 + (b*16 + lr)*8]);                             \
      _Pragma("unroll")                                                        \
      for (int a = 0; a < 4; ++a)                                              \
        _Pragma("unroll")                                                      \
        for (int b = 0; b < 4; ++b)                                            \
          acc[a][b] = __builtin_amdgcn_mfma_f32_16x16x32_bf16(                 \
              af[a][(j)*2 + kk], bfr[b], acc[a][b], 0, 0, 0);                  \
    }                                                                          \
  } while (0)

#define STAGE_W(j, NSTR) do {                                                  \
    asm volatile("s_waitcnt vmcnt(" NSTR ")" ::: "memory");                    \
    __builtin_amdgcn_s_barrier();                                              \
    __builtin_amdgcn_sched_barrier(0);                                         \
  } while (0)

#define ACC_ZERO() do {                                                        \
    _Pragma("unroll")                                                          \
    for (int a = 0; a < 4; ++a)                                                \
      _Pragma("unroll")                                                        \
      for (int b = 0; b < 4; ++b) acc[a][b] = (f32x4){0.f,0.f,0.f,0.f};        \
  } while (0)

  // ---- epilogue: bias, logit store (LDS-transposed), (max,sumexp) -> part ----
  auto epi = [&](int tt) {
    const bool hg = (tt < NCBG);
    const float* bia = hg ? bg : bs;
    const int C = hg ? NG_ : NS_;
    float* outp = hg ? out : out + (size_t)B_*NG_;
    float2* part = hg ? Pg : Ps;
    const int cb = hg ? tt : tt - NCBG;
    const int c0 = cb * 64;

    float bv[4]; bool okc[4];
    #pragma unroll
    for (int b = 0; b < 4; ++b) {
      int col = c0 + b*16 + lr;
      okc[b] = (col < C);
      bv[b] = okc[b] ? bia[col] : 0.f;
    }
    const int cq = (lane & 15) * 4;          // col quad for transposed store
    const bool sok = (c0 + cq < C);
    #pragma unroll
    for (int a = 0; a < 4; ++a) {
      // stats + LDS write for this 16-row chunk
      #pragma unroll
      for (int i = 0; i < 4; ++i) {
        int rloc = lg*4 + i;
        float v[4], mx = -3.0e38f;
        #pragma unroll
        for (int b = 0; b < 4; ++b) {
          v[b] = okc[b] ? (acc[a][b][i] + bv[b]) : -3.0e38f;
          mx = fmaxf(mx, v[b]);
          eplds[w][rloc*68 + b*16 + lr] = v[b];
        }
        #pragma unroll
        for (int off = 1; off < 16; off <<= 1) mx = fmaxf(mx, __shfl_xor(mx, off));
        float s = 0.f;
        #pragma unroll
        for (int b = 0; b < 4; ++b) s += __expf(v[b] - mx);
        #pragma unroll
        for (int off = 1; off < 16; off <<= 1) s += __shfl_xor(s, off);
        if (lr == 0) part[(size_t)cb*512 + w*64 + a*16 + lg*4 + i] = make_float2(mx, s);
      }
      // transposed contiguous stores: 4 instrs, 4 rows x 256B each
      #pragma unroll
      for (int it = 0; it < 4; ++it) {
        int rloc = it*4 + (lane >> 4);
        float4 v4 = *reinterpret_cast<const float4*>(&eplds[w][rloc*68 + cq]);
        if (sok)
          *reinterpret_cast<float4*>(&outp[(size_t)(w*64 + a*16 + rloc)*C + c0 + cq]) = v4;
      }
    }
  };

  // ---- tile 0 (strict waits: only DMAs outstanding) ----
  {
    const int tl = 0;
    ACC_ZERO();
    STAGE_W(0, "4"); dma(5); MFMA10(0);
    STAGE_W(1, "4"); dma(6); MFMA10(1);
    STAGE_W(2, "4"); dma(7); MFMA10(2);
    STAGE_W(3, "4"); dma(8); MFMA10(3);
    STAGE_W(4, "4"); dma(9); MFMA10(4);
    epi(bid);
  }
  // ---- middle tiles (uniform vmcnt(40): stores never forced to drain) ----
  for (int tl = 1; tl < nt - 1; ++tl) {
    ACC_ZERO();
    STAGE_W(0, "40"); dma(tl*5 + 5); MFMA10(0);
    STAGE_W(1, "40"); dma(tl*5 + 6); MFMA10(1);
    STAGE_W(2, "40"); dma(tl*5 + 7); MFMA10(2);
    STAGE_W(3, "40"); dma(tl*5 + 8); MFMA10(3);
    STAGE_W(4, "40"); dma(tl*5 + 9); MFMA10(4);
    epi(bid + tl*256);
  }
  // ---- last tile (descending strict counts, no new DMA) ----
  {
    const int tl = nt - 1;
    ACC_ZERO();
    STAGE_W(0, "40"); MFMA10(0);
    STAGE_W(1, "39"); MFMA10(1);
    STAGE_W(2, "38"); MFMA10(2);
    STAGE_W(3, "37"); MFMA10(3);
    STAGE_W(4, "36"); MFMA10(4);
    epi(bid + tl*256);
  }
#undef MFMA10
#undef STAGE_W
#undef ACC_ZERO
}

// ---------------- k5b: combine tile-major (m,s) partials -> lse[1024] ----------------
__global__ __launch_bounds__(256) void k5b(
    const float2* __restrict__ Pg, const float2* __restrict__ Ps,
    float* __restrict__ lse)
{
  const int blk = blockIdx.x;            // 0..127
  const bool hg = (blk < 64);
  const float2* p = hg ? Pg : Ps;
  const int n = hg ? NCBG : NCBS;
  const int r0 = (hg ? blk : blk - 64) * 8;
  const int tid = threadIdx.x;
  const int rr = tid & 7;
  const int row = r0 + rr;

  float m = -3.0e38f, s = 0.f;
  for (int t = tid >> 3; t < n; t += 32) {
    float2 v = p[(size_t)t*512 + row];
    float mn = fmaxf(m, v.x);
    s = s*__expf(m - mn) + v.y*__expf(v.x - mn);
    m = mn;
  }
  #pragma unroll
  for (int off = 8; off < 64; off <<= 1) {
    float m2 = __shfl_xor(m, off), s2 = __shfl_xor(s, off);
    float mn = fmaxf(m, m2);
    s = s*__expf(m - mn) + s2*__expf(m2 - mn);
    m = mn;
  }
  __shared__ float ms[4][8], ss[4][8];
  const int wv = tid >> 6;
  if ((tid & 63) < 8) { ms[wv][tid & 7] = m; ss[wv][tid & 7] = s; }
  __syncthreads();
  if (tid < 8) {
    float M = ms[0][tid], S = ss[0][tid];
    #pragma unroll
    for (int ww = 1; ww < 4; ++ww) {
      float mn = fmaxf(M, ms[ww][tid]);
      S = S*__expf(M - mn) + ss[ww][tid]*__expf(ms[ww][tid] - mn);
      M = mn;
    }
    lse[(hg ? 0 : 512) + r0 + tid] = M + __logf(S);
  }
}

// ---------------- K4: out -= lse[row], float4 ----------------
__global__ void k4_sub(float* __restrict__ out, const float* __restrict__ lse)
{
  const size_t g4 = (size_t)B_*NG_/4;
  const size_t total4 = g4 + (size_t)B_*NS_/4;
  size_t stride = (size_t)gridDim.x * blockDim.x;
  for (size_t i4 = (size_t)blockIdx.x*blockDim.x + threadIdx.x; i4 < total4; i4 += stride) {
    int row;
    if (i4 < g4) row = (int)(i4 / (NG_/4));
    else         row = B_ + (int)((i4 - g4) / (NS_/4));
    float l = lse[row];
    float4 v = reinterpret_cast<float4*>(out)[i4];
    v.x -= l; v.y -= l; v.z -= l; v.w -= l;
    reinterpret_cast<float4*>(out)[i4] = v;
  }
}

// =====================================================================
extern "C" void kernel_launch(void* const* d_in, const int* in_sizes, int n_in,
                              void* d_out, int out_size, void* d_ws, size_t ws_size,
                              hipStream_t stream)
{
  const float* x    = (const float*)d_in[0];
  const int*   ei   = (const int*)  d_in[1];
  const int*   et   = (const int*)  d_in[2];
  const float* Wrel = (const float*)d_in[3];
  const float* W0   = (const float*)d_in[4];
  const float* Wg   = (const float*)d_in[5];
  const float* bg   = (const float*)d_in[6];
  const float* Ws   = (const float*)d_in[7];
  const float* bs   = (const float*)d_in[8];
  float* out = (float*)d_out;

  // ws layout (bytes): Ybf | X0H | P1 | Pg | Ps | LSE | Wttg | Wtts (~60.3 MB)
  char* p = (char*)d_ws;
  unsigned short* Ybf = (unsigned short*)p;  p += (size_t)B_*YLD*2;
  unsigned short* X0H = (unsigned short*)p;  p += (size_t)B_*XLD*2;
  float*  P1  = (float*)p;                   p += (size_t)8*B_*PLD*4;
  float2* Pg  = (float2*)p;                  p += (size_t)NCBG*512*8;
  float2* Ps  = (float2*)p;                  p += (size_t)NCBS*512*8;
  float*  LSE = (float*)p;                   p += 4096;
  unsigned short* Wttg = (unsigned short*)p; p += (size_t)40*CPADG*16;
  unsigned short* Wtts = (unsigned short*)p;

  // W pre-transpose (octet-major bf16)
  wtrans2<<<dim3(CPADG/64, 5), 256, 0, stream>>>(Wg, NG_, CPADG, Wttg);
  wtrans2<<<dim3(CPADS/64, 5), 256, 0, stream>>>(Ws, NS_, CPADS, Wtts);

  k1a_coef_y<<<B_, 256, 0, stream>>>(x, ei, et, Ybf);

  // k1b: P1[z] = Y @ [Wrel;W0] partials (z-split over 33 K-tiles)
  gemm_k1b<<<2*5*8, 256, 0, stream>>>(Ybf, YLD, Wrel, W0, P1, 8);
  k1c_reduce<<<(B_*XLD + 255)/256, 256, 0, stream>>>(P1, 8, X0H);

  // heads: logits (+bias) -> out, per-tile (max,sumexp) -> Pg/Ps
  gemm10<<<256, 512, 0, stream>>>(X0H, Wttg, Wtts, bg, bs, out, Pg, Ps);

  k5b<<<128, 256, 0, stream>>>(Pg, Ps, LSE);
  k4_sub<<<2048, 256, 0, stream>>>(out, LSE);
}

// Round 13
// 254.806 us; speedup vs baseline: 1.0569x; 1.0569x over previous
//
#include <hip/hip_runtime.h>
#include <hip/hip_bf16.h>
#include <math.h>

#define B_ 512
#define N_ 32
#define D_ 300
#define R_ 6
#define E_ 256
#define NG_ 50000
#define NS_ 25000

#define KTOT 2100      // 6*300 (Wrel) + 300 (W0)
#define YLD  2112      // Y bf16 leading dim (33*64)
#define XLD  320       // X0H bf16 leading dim (5*64)
#define PLD  304       // k1b partial leading dim (fp32)
#define NCBG 782       // ceil(50000/64)
#define NCBS 391       // ceil(25000/64)
#define CPADG (NCBG*64)   // 50048
#define CPADS (NCBS*64)   // 25024
#define NTILE (NCBG+NCBS) // 1173

typedef __attribute__((ext_vector_type(8))) short short8;
typedef __attribute__((ext_vector_type(4))) float f32x4;

__device__ __forceinline__ unsigned short f2bf(float f) {
  __hip_bfloat16 h = __float2bfloat16(f);
  return *reinterpret_cast<unsigned short*>(&h);
}

__device__ __forceinline__ void gload_lds16(const unsigned short* g, unsigned short* l) {
  __builtin_amdgcn_global_load_lds(
      (const __attribute__((address_space(1))) void*)g,
      (__attribute__((address_space(3))) void*)l,
      16, 0, 0);
}

// ---------------- K1a: collapse graph to Y[b, 2112] bf16 (zero k-pad) ----------------
__global__ __launch_bounds__(256) void k1a_coef_y(
    const float* __restrict__ x, const int* __restrict__ ei,
    const int* __restrict__ et, unsigned short* __restrict__ Y)
{
  int b = blockIdx.x;
  int tid = threadIdx.x;
  __shared__ int srcs[E_], dsts[E_], ets[E_];
  __shared__ int degc[R_*N_];
  __shared__ float coef[R_*N_];

  srcs[tid] = ei[b*2*E_ + tid];
  dsts[tid] = ei[b*2*E_ + E_ + tid];
  ets[tid]  = et[b*E_ + tid];
  if (tid < R_*N_) { degc[tid] = 0; coef[tid] = 0.0f; }
  __syncthreads();

  atomicAdd(&degc[ets[tid]*N_ + dsts[tid]], 1);
  __syncthreads();

  if (dsts[tid] == 0) {
    int r = ets[tid];
    float ds = 1.0f + (float)degc[r*N_ + srcs[tid]];
    float dd = 1.0f + (float)degc[r*N_ + 0];
    atomicAdd(&coef[r*N_ + srcs[tid]], rsqrtf(ds*dd));
  }
  if (tid < R_) {
    atomicAdd(&coef[tid*N_ + 0], 1.0f/(1.0f + (float)degc[tid*N_]));
  }
  __syncthreads();

  const float* xb = x + (size_t)b*N_*D_;
  unsigned short* Yb = Y + (size_t)b*YLD;
  for (int k = tid; k < D_; k += 256) {
    #pragma unroll
    for (int r = 0; r < R_; ++r) {
      float acc = 0.0f;
      for (int n = 0; n < N_; ++n) {
        float c = coef[r*N_ + n];          // uniform across threads
        if (c != 0.0f) acc += c * xb[n*D_ + k];
      }
      Yb[r*D_ + k] = f2bf(acc);
    }
    Yb[6*D_ + k] = f2bf(xb[k]);            // x[b,0,:] for the W0 term
  }
  if (tid < YLD - KTOT) Yb[KTOT + tid] = 0;
}

// ---------------- k1b gemm (round-5 proven): BM=256, BN=64, BK=64 ----------------
__global__ __launch_bounds__(256, 3) void gemm_k1b(
    const unsigned short* __restrict__ A, int lda,
    const float* __restrict__ B0, const float* __restrict__ B1,
    float* __restrict__ P1, int nz)
{
  __shared__ unsigned short As[256*64];
  __shared__ unsigned short Bs[64*80];

  const int tid  = threadIdx.x;
  const int lane = tid & 63, wid = tid >> 6;
  const int lr = lane & 15, lg = lane >> 4;

  int id = blockIdx.x;          // 2 mb * 5 cb * nz
  int mb = id & 1; id >>= 1;
  int cb = id % 5, z = id / 5;
  const int m0 = mb*256, c0 = cb*64;
  const int ksplit = 6*D_;

  const int r8 = lane >> 3, sl = lane & 7;
  const int c_l = tid & 63, ob = tid >> 6;
  const int gcol = c0 + c_l;
  const bool cok = (gcol < D_);

  f32x4 acc[4][4];
  #pragma unroll
  for (int a = 0; a < 4; ++a)
    #pragma unroll
    for (int b = 0; b < 4; ++b) acc[a][b] = (f32x4){0.f,0.f,0.f,0.f};

  for (int t = z; t < 33; t += nz) {
    const int kt = t * 64;
    __syncthreads();

    #pragma unroll
    for (int i = 0; i < 8; ++i) {
      int row_l = wid*64 + i*8 + r8;
      int sslot = sl ^ (row_l & 7);
      gload_lds16(A + (size_t)(m0 + row_l)*lda + kt + sslot*8, &As[(wid*64 + i*8)*64]);
    }

    #pragma unroll
    for (int it = 0; it < 2; ++it) {
      int o  = ob + it*4;
      int kb = kt + o*8;
      unsigned short u[8];
      #pragma unroll
      for (int j = 0; j < 8; ++j) {
        int k = kb + j;
        float v = 0.f;
        if (cok && k < KTOT)
          v = (k < ksplit) ? B0[(size_t)k*D_ + gcol]
                           : B1[(size_t)(k - ksplit)*D_ + gcol];
        u[j] = f2bf(v);
      }
      *reinterpret_cast<short8*>(&Bs[c_l*80 + ((o ^ (c_l & 7)) << 3)]) =
          *reinterpret_cast<const short8*>(u);
    }

    __syncthreads();

    #pragma unroll
    for (int kk = 0; kk < 2; ++kk) {
      const int q = kk*4 + lg;
      short8 bfr[4];
      #pragma unroll
      for (int b = 0; b < 4; ++b) {
        int col = b*16 + lr;
        bfr[b] = *reinterpret_cast<const short8*>(&Bs[col*80 + ((q ^ (col & 7)) << 3)]);
      }
      #pragma unroll
      for (int a = 0; a < 4; ++a) {
        int row = wid*64 + a*16 + lr;
        short8 af = *reinterpret_cast<const short8*>(&As[row*64 + ((q ^ (row & 7)) << 3)]);
        #pragma unroll
        for (int b = 0; b < 4; ++b)
          acc[a][b] = __builtin_amdgcn_mfma_f32_16x16x32_bf16(af, bfr[b], acc[a][b], 0, 0, 0);
      }
    }
  }

  float* o = P1 + (size_t)z * (size_t)B_ * PLD;
  #pragma unroll
  for (int a = 0; a < 4; ++a) {
    int row = m0 + wid*64 + a*16 + lg*4;
    #pragma unroll
    for (int b = 0; b < 4; ++b) {
      int col = c0 + b*16 + lr;
      if (col < D_) {
        #pragma unroll
        for (int i = 0; i < 4; ++i)
          o[(size_t)(row + i)*PLD + col] = acc[a][b][i];
      }
    }
  }
}

// ---------------- K1c: reduce z-partials, leaky, emit bf16 X0H [512][320] ----------------
__global__ __launch_bounds__(256) void k1c_reduce(
    const float* __restrict__ part, int nz, unsigned short* __restrict__ X0Hbf)
{
  int idx = blockIdx.x*256 + threadIdx.x;
  if (idx >= B_*XLD) return;
  int m = idx / XLD, c = idx % XLD;
  float v = 0.f;
  if (c < D_) {
    for (int zz = 0; zz < nz; ++zz) v += part[(size_t)zz*B_*PLD + (size_t)m*PLD + c];
    v = (v >= 0.f) ? v : 0.1f*v;
  }
  X0Hbf[idx] = f2bf(v);
}

// ---------------- wtrans2: W[300][C] fp32 -> Wtt octet-major bf16 ----------------
// Wtt unit (16B) index = k_oct * Cpad + col; holds W[k_oct*8 .. +7][col] as 8 bf16.
__global__ __launch_bounds__(256) void wtrans2(
    const float* __restrict__ W, int C, int Cpad, unsigned short* __restrict__ Wtt)
{
  __shared__ float lds[64][65];
  const int tid = threadIdx.x;
  const int c0 = blockIdx.x * 64;
  const int k0 = blockIdx.y * 64;
  const int col = tid & 63;
  const int w = tid >> 6;

  #pragma unroll
  for (int p = 0; p < 16; ++p) {
    int kl = w*16 + p;
    int k = k0 + kl;
    float v = 0.f;
    if (k < D_ && c0 + col < C) v = W[(size_t)k*C + c0 + col];
    lds[kl][col] = v;
  }
  __syncthreads();

  #pragma unroll
  for (int q2 = 0; q2 < 2; ++q2) {
    int octl = w*2 + q2;
    unsigned short u[8];
    #pragma unroll
    for (int j = 0; j < 8; ++j) u[j] = f2bf(lds[octl*8 + j][col]);
    size_t goct = (size_t)(k0 >> 3) + octl;
    *reinterpret_cast<short8*>(&Wtt[(goct*Cpad + c0 + col) * 8]) =
        *reinterpret_cast<const short8*>(u);
  }
}

// ---------------- gemm11: heads, two-pass recompute log-softmax ----------------
// BM=128 per block; 4 mb-blocks (consecutive swizzled ids -> same XCD -> W L2-shared)
// cover all 512 rows. BN=64, ONE col-tile per block. 4 waves x 32 rows;
// af[2][10] in regs; all 5 B-stages DMA'd up front into 40 KB LDS;
// per-stage counted vmcnt + raw s_barrier (no store-drain hazard).
// MODE 0: per-row (max, sumexp) stats -> part (no logits write).
// MODE 1: out[row][col] = acc + bias - lse[row].
template<int MODE>
__global__ __launch_bounds__(256, 3) void gemm11(
    const unsigned short* __restrict__ X0H,
    const unsigned short* __restrict__ Wttg, const unsigned short* __restrict__ Wtts,
    const float* __restrict__ bg, const float* __restrict__ bs,
    float* __restrict__ out, float2* __restrict__ Pg, float2* __restrict__ Ps,
    const float* __restrict__ lse)
{
  __shared__ unsigned short Bs[5][4096];   // 5 stages x 8 KB

  // bijective XCD-chunked swizzle (grid = 4*NTILE = 4692)
  int bid = blockIdx.x;
  int nwg = gridDim.x;
  int q = nwg >> 3, r = nwg & 7, xcd = bid & 7, loc = bid >> 3;
  int id = (xcd < r ? xcd*(q+1) : r*(q+1) + (xcd-r)*q) + loc;

  const int mb = id & 3;          // 4 m-blocks of 128 rows; same XCD -> W L2-shared
  const int tt = id >> 2;         // 0..1172
  const bool hg = (tt < NCBG);
  const int cb = hg ? tt : tt - NCBG;
  const int c0 = cb*64;
  const unsigned short* Wtt = hg ? Wttg : Wtts;
  const size_t cp = hg ? CPADG : CPADS;
  const int C = hg ? NG_ : NS_;
  const float* bia = hg ? bg : bs;
  const int m0 = mb*128;

  const int tid = threadIdx.x;
  const int lane = tid & 63, w = tid >> 6;
  const int lr = lane & 15, lg = lane >> 4;

  // ---- A fragments (oldest vmem: retired by any later counted wait) ----
  short8 af[2][10];
  #pragma unroll
  for (int a = 0; a < 2; ++a) {
    const unsigned short* Ar = X0H + (size_t)(m0 + w*32 + a*16 + lr)*XLD + lg*8;
    #pragma unroll
    for (int ks = 0; ks < 10; ++ks)
      af[a][ks] = *reinterpret_cast<const short8*>(Ar + ks*32);
  }
  __builtin_amdgcn_sched_barrier(0);

  // ---- issue ALL B DMAs (2 per wave per stage; 8 KB/stage block-wide) ----
  #pragma unroll
  for (int j = 0; j < 5; ++j) {
    #pragma unroll
    for (int i2 = 0; i2 < 2; ++i2) {
      int o = w*2 + i2;   // octet 0..7 within stage
      const unsigned short* g = Wtt + ((size_t)(j*8 + o)*cp + (size_t)c0 + lane)*8;
      gload_lds16(g, &Bs[j][o*512]);
    }
  }
  __builtin_amdgcn_sched_barrier(0);

  f32x4 acc[2][4];
  #pragma unroll
  for (int a = 0; a < 2; ++a)
    #pragma unroll
    for (int b = 0; b < 4; ++b) acc[a][b] = (f32x4){0.f,0.f,0.f,0.f};

#define STAGE11(j, NSTR) do {                                                  \
    asm volatile("s_waitcnt vmcnt(" NSTR ")" ::: "memory");                    \
    __builtin_amdgcn_s_barrier();                                              \
    __builtin_amdgcn_sched_barrier(0);                                         \
    _Pragma("unroll")                                                          \
    for (int kk = 0; kk < 2; ++kk) {                                           \
      short8 bfr[4];                                                           \
      _Pragma("unroll")                                                        \
      for (int b = 0; b < 4; ++b)                                              \
        bfr[b] = *reinterpret_cast<const short8*>(                             \
            &Bs[j][(kk*4 + lg)*512 + (b*16 + lr)*8]);                          \
      _Pragma("unroll")                                                        \
      for (int a = 0; a < 2; ++a)                                              \
        _Pragma("unroll")                                                      \
        for (int b = 0; b < 4; ++b)                                            \
          acc[a][b] = __builtin_amdgcn_mfma_f32_16x16x32_bf16(                 \
              af[a][(j)*2 + kk], bfr[b], acc[a][b], 0, 0, 0);                  \
    }                                                                          \
  } while (0)

  STAGE11(0, "8");
  STAGE11(1, "6");
  STAGE11(2, "4");
  STAGE11(3, "2");
  STAGE11(4, "0");
#undef STAGE11

  // ---- epilogue ----
  float bv[4]; bool okc[4];
  #pragma unroll
  for (int b = 0; b < 4; ++b) {
    int col = c0 + b*16 + lr;
    okc[b] = (col < C);
    bv[b] = okc[b] ? bia[col] : 0.f;
  }

  if constexpr (MODE == 0) {
    float2* part = hg ? Pg : Ps;
    #pragma unroll
    for (int a = 0; a < 2; ++a) {
      #pragma unroll
      for (int i = 0; i < 4; ++i) {
        int row = m0 + w*32 + a*16 + lg*4 + i;
        float v[4], mx = -3.0e38f;
        #pragma unroll
        for (int b = 0; b < 4; ++b) {
          v[b] = okc[b] ? (acc[a][b][i] + bv[b]) : -3.0e38f;
          mx = fmaxf(mx, v[b]);
        }
        #pragma unroll
        for (int off = 1; off < 16; off <<= 1) mx = fmaxf(mx, __shfl_xor(mx, off));
        float s = 0.f;
        #pragma unroll
        for (int b = 0; b < 4; ++b) s += __expf(v[b] - mx);
        #pragma unroll
        for (int off = 1; off < 16; off <<= 1) s += __shfl_xor(s, off);
        if (lr == 0) part[(size_t)cb*512 + row] = make_float2(mx, s);
      }
    }
  } else {
    float* outp = hg ? out : out + (size_t)B_*NG_;
    const float* lp = lse + (hg ? 0 : 512);
    #pragma unroll
    for (int a = 0; a < 2; ++a) {
      #pragma unroll
      for (int i = 0; i < 4; ++i) {
        int row = m0 + w*32 + a*16 + lg*4 + i;
        float L = lp[row];
        #pragma unroll
        for (int b = 0; b < 4; ++b) {
          if (okc[b])
            outp[(size_t)row*C + c0 + b*16 + lr] = acc[a][b][i] + bv[b] - L;
        }
      }
    }
  }
}

// ---------------- k5b: combine tile-major (m,s) partials -> lse[1024] ----------------
__global__ __launch_bounds__(256) void k5b(
    const float2* __restrict__ Pg, const float2* __restrict__ Ps,
    float* __restrict__ lse)
{
  const int blk = blockIdx.x;            // 0..127
  const bool hg = (blk < 64);
  const float2* p = hg ? Pg : Ps;
  const int n = hg ? NCBG : NCBS;
  const int r0 = (hg ? blk : blk - 64) * 8;
  const int tid = threadIdx.x;
  const int rr = tid & 7;
  const int row = r0 + rr;

  float m = -3.0e38f, s = 0.f;
  for (int t = tid >> 3; t < n; t += 32) {
    float2 v = p[(size_t)t*512 + row];
    float mn = fmaxf(m, v.x);
    s = s*__expf(m - mn) + v.y*__expf(v.x - mn);
    m = mn;
  }
  #pragma unroll
  for (int off = 8; off < 64; off <<= 1) {
    float m2 = __shfl_xor(m, off), s2 = __shfl_xor(s, off);
    float mn = fmaxf(m, m2);
    s = s*__expf(m - mn) + s2*__expf(m2 - mn);
    m = mn;
  }
  __shared__ float ms[4][8], ss[4][8];
  const int wv = tid >> 6;
  if ((tid & 63) < 8) { ms[wv][tid & 7] = m; ss[wv][tid & 7] = s; }
  __syncthreads();
  if (tid < 8) {
    float M = ms[0][tid], S = ss[0][tid];
    #pragma unroll
    for (int ww = 1; ww < 4; ++ww) {
      float mn = fmaxf(M, ms[ww][tid]);
      S = S*__expf(M - mn) + ss[ww][tid]*__expf(ms[ww][tid] - mn);
      M = mn;
    }
    lse[(hg ? 0 : 512) + r0 + tid] = M + __logf(S);
  }
}

// =====================================================================
extern "C" void kernel_launch(void* const* d_in, const int* in_sizes, int n_in,
                              void* d_out, int out_size, void* d_ws, size_t ws_size,
                              hipStream_t stream)
{
  const float* x    = (const float*)d_in[0];
  const int*   ei   = (const int*)  d_in[1];
  const int*   et   = (const int*)  d_in[2];
  const float* Wrel = (const float*)d_in[3];
  const float* W0   = (const float*)d_in[4];
  const float* Wg   = (const float*)d_in[5];
  const float* bg   = (const float*)d_in[6];
  const float* Ws   = (const float*)d_in[7];
  const float* bs   = (const float*)d_in[8];
  float* out = (float*)d_out;

  // ws layout (bytes): Ybf | X0H | P1 | Pg | Ps | LSE | Wttg | Wtts (~60.3 MB)
  char* p = (char*)d_ws;
  unsigned short* Ybf = (unsigned short*)p;  p += (size_t)B_*YLD*2;
  unsigned short* X0H = (unsigned short*)p;  p += (size_t)B_*XLD*2;
  float*  P1  = (float*)p;                   p += (size_t)8*B_*PLD*4;
  float2* Pg  = (float2*)p;                  p += (size_t)NCBG*512*8;
  float2* Ps  = (float2*)p;                  p += (size_t)NCBS*512*8;
  float*  LSE = (float*)p;                   p += 4096;
  unsigned short* Wttg = (unsigned short*)p; p += (size_t)40*CPADG*16;
  unsigned short* Wtts = (unsigned short*)p;

  // W pre-transpose (octet-major bf16)
  wtrans2<<<dim3(CPADG/64, 5), 256, 0, stream>>>(Wg, NG_, CPADG, Wttg);
  wtrans2<<<dim3(CPADS/64, 5), 256, 0, stream>>>(Ws, NS_, CPADS, Wtts);

  k1a_coef_y<<<B_, 256, 0, stream>>>(x, ei, et, Ybf);

  // k1b: P1[z] = Y @ [Wrel;W0] partials (z-split over 33 K-tiles)
  gemm_k1b<<<2*5*8, 256, 0, stream>>>(Ybf, YLD, Wrel, W0, P1, 8);
  k1c_reduce<<<(B_*XLD + 255)/256, 256, 0, stream>>>(P1, 8, X0H);

  // pass1: per-tile row stats -> Pg/Ps (no logits write)
  gemm11<0><<<4*NTILE, 256, 0, stream>>>(X0H, Wttg, Wtts, bg, bs,
                                         nullptr, Pg, Ps, nullptr);
  k5b<<<128, 256, 0, stream>>>(Pg, Ps, LSE);

  // pass2: recompute logits, write out = acc + bias - lse
  gemm11<1><<<4*NTILE, 256, 0, stream>>>(X0H, Wttg, Wtts, bg, bs,
                                         out, nullptr, nullptr, LSE);
}